// Round 2
// baseline (55.479 us; speedup 1.0000x reference)
//
#include <hip/hip_runtime.h>

#define LDIM 256
#define SDIM 64
#define DDIM 128
#define HDIM 512

typedef __attribute__((ext_vector_type(8))) __bf16 bf16x8;
typedef __attribute__((ext_vector_type(4))) float f32x4;
typedef __attribute__((ext_vector_type(4))) float float4v;
typedef __attribute__((ext_vector_type(4))) unsigned int u32x4;

__device__ __forceinline__ unsigned short f2bf(float f) {
    union { float f; unsigned int u; } v; v.f = f;
    unsigned int u = v.u;
    u += 0x7FFFu + ((u >> 16) & 1u);   // round-to-nearest-even
    return (unsigned short)(u >> 16);
}
__device__ __forceinline__ float bf2f(unsigned short b) {
    union { unsigned int u; float f; } v; v.u = ((unsigned int)b) << 16;
    return v.f;
}

// swizzle on ushort index: XOR bits 3..5 with (row&7)  == byte ^= (row&7)<<4
#define SWZ(idx, row) ((idx) ^ (((row) & 7) << 3))

// ---------------------------------------------------------------------------
// Prep: transpose + fp32->bf16 convert the 4 weight matrices into ws.
// ws layout (ushort units): Wt1[512][128] @0, Wt2[128][512] @65536,
//                           Wt3[512][256] @131072, Wt4[128][512] @262144
// ---------------------------------------------------------------------------
__global__ __launch_bounds__(256) void kprep(
    const float* __restrict__ W1, const float* __restrict__ W2,
    const float* __restrict__ W3, const float* __restrict__ W4,
    unsigned short* __restrict__ ws) {
    __shared__ unsigned short tile[32][33];
    int b = blockIdx.x;
    const float* src; unsigned short* dst; int K, N, tr, tc;
    if (b < 64)        { src = W1; dst = ws;          K = 128; N = 512; int t = b;       tr = t >> 4; tc = t & 15; }
    else if (b < 128)  { src = W2; dst = ws + 65536;  K = 512; N = 128; int t = b - 64;  tr = t >> 2; tc = t & 3;  }
    else if (b < 256)  { src = W3; dst = ws + 131072; K = 256; N = 512; int t = b - 128; tr = t >> 4; tc = t & 15; }
    else               { src = W4; dst = ws + 262144; K = 512; N = 128; int t = b - 256; tr = t >> 2; tc = t & 3;  }
    int tid = threadIdx.x;
#pragma unroll
    for (int i = 0; i < 4; i++) {
        int e = tid + i * 256;
        int r = e >> 5, c = e & 31;
        tile[r][c] = f2bf(src[(tr * 32 + r) * N + tc * 32 + c]);
    }
    __syncthreads();
#pragma unroll
    for (int i = 0; i < 4; i++) {
        int e = tid + i * 256;
        int r = e >> 5, c = e & 31;      // r: n-in-tile, c: k-in-tile
        dst[(tc * 32 + r) * K + tr * 32 + c] = tile[c][r];
    }
}

// ---------------------------------------------------------------------------
// Fused DeepSets block: one block per l (64 rows), 4 waves.
// ---------------------------------------------------------------------------
__global__ __launch_bounds__(256, 1) void kmain(
    const float* __restrict__ x,
    const float* __restrict__ b1, const float* __restrict__ b2,
    const float* __restrict__ b3, const float* __restrict__ b4,
    const unsigned short* __restrict__ ws, float* __restrict__ out) {

    __shared__ __align__(16) unsigned short xs[SDIM * DDIM];   // 16 KB  x (bf16)
    __shared__ __align__(16) unsigned short cs[SDIM * DDIM];   // 16 KB  combined
    __shared__ __align__(16) unsigned short h1[SDIM * HDIM];   // 64 KB  hidden
    __shared__ __align__(16) unsigned short cm[SDIM * DDIM];   // 16 KB  cm

    const unsigned short* Wt1 = ws;
    const unsigned short* Wt2 = ws + 65536;
    const unsigned short* Wt3 = ws + 131072;
    const unsigned short* Wt4 = ws + 262144;

    const int tid  = threadIdx.x;
    const int lane = tid & 63;
    const int wid  = tid >> 6;
    const int l    = blockIdx.x;
    const int lr   = lane & 15;          // frag row (A) / col (B,C/D)
    const int lk   = (lane >> 4) << 3;   // frag k-offset {0,8,16,24}
    const int lq   = (lane >> 4) << 2;   // C/D row group {0,4,8,12}
    const float* xg = x + l * SDIM * DDIM;

    // ---- stage x -> xs (bf16, swizzled), 16B chunks ----
#pragma unroll
    for (int it = 0; it < 4; it++) {
        int ch   = tid + it * 256;       // chunk of 8 elements
        int base = ch * 8;
        int row  = base >> 7;
        float4v v0 = *(const float4v*)(xg + base);
        float4v v1 = *(const float4v*)(xg + base + 4);
        u32x4 p;
        p.x = (unsigned int)f2bf(v0.x) | ((unsigned int)f2bf(v0.y) << 16);
        p.y = (unsigned int)f2bf(v0.z) | ((unsigned int)f2bf(v0.w) << 16);
        p.z = (unsigned int)f2bf(v1.x) | ((unsigned int)f2bf(v1.y) << 16);
        p.w = (unsigned int)f2bf(v1.z) | ((unsigned int)f2bf(v1.w) << 16);
        *(u32x4*)(&xs[SWZ(base, row)]) = p;
    }
    __syncthreads();

    // ---- masked all-pairs max via top-2: cs[j][d] = max(0, max_{i!=j} x[i][d]) ----
    if (tid < 128) {
        int d = tid;
        float m1 = -1e30f, m2 = -1e30f; int i1 = -1;
        for (int i = 0; i < 64; i++) {
            float v = bf2f(xs[SWZ(i * DDIM + d, i)]);
            if (v > m1) { m2 = m1; m1 = v; i1 = i; }
            else if (v > m2) { m2 = v; }
        }
        for (int j = 0; j < 64; j++) {
            float r = (j == i1) ? m2 : m1;
            r = fmaxf(r, 0.0f);
            cs[SWZ(j * DDIM + d, j)] = f2bf(r);
        }
    }
    __syncthreads();

    // ---- GEMM1: h1 = relu(cs[64x128] @ W1[128x512] + b1); wave w -> n in [w*128, w*128+128) ----
    {
        f32x4 acc[4][8];
#pragma unroll
        for (int m = 0; m < 4; m++)
#pragma unroll
            for (int n = 0; n < 8; n++) acc[m][n] = (f32x4)0.0f;
#pragma unroll
        for (int ks = 0; ks < 4; ks++) {
            bf16x8 a[4];
#pragma unroll
            for (int m = 0; m < 4; m++) {
                int row = m * 16 + lr;
                a[m] = *(const bf16x8*)(&cs[SWZ(row * DDIM + ks * 32 + lk, row)]);
            }
#pragma unroll
            for (int n = 0; n < 8; n++) {
                int ncol = wid * 128 + n * 16 + lr;
                bf16x8 bfr = *(const bf16x8*)(&Wt1[ncol * 128 + ks * 32 + lk]);
#pragma unroll
                for (int m = 0; m < 4; m++)
                    acc[m][n] = __builtin_amdgcn_mfma_f32_16x16x32_bf16(a[m], bfr, acc[m][n], 0, 0, 0);
            }
        }
#pragma unroll
        for (int n = 0; n < 8; n++) {
            int col = wid * 128 + n * 16 + lr;
            float bias = b1[col];
#pragma unroll
            for (int m = 0; m < 4; m++)
#pragma unroll
                for (int r = 0; r < 4; r++) {
                    int row = m * 16 + lq + r;
                    float v = fmaxf(acc[m][n][r] + bias, 0.0f);
                    h1[SWZ(row * HDIM + col, row)] = f2bf(v);
                }
        }
    }
    __syncthreads();

    // ---- GEMM2: cm = h1[64x512] @ W2[512x128] + b2; wave w -> n in [w*32, w*32+32) ----
    {
        f32x4 acc[4][2];
#pragma unroll
        for (int m = 0; m < 4; m++) { acc[m][0] = (f32x4)0.0f; acc[m][1] = (f32x4)0.0f; }
#pragma unroll
        for (int ks = 0; ks < 16; ks++) {
            bf16x8 a[4];
#pragma unroll
            for (int m = 0; m < 4; m++) {
                int row = m * 16 + lr;
                a[m] = *(const bf16x8*)(&h1[SWZ(row * HDIM + ks * 32 + lk, row)]);
            }
#pragma unroll
            for (int n = 0; n < 2; n++) {
                int ncol = wid * 32 + n * 16 + lr;
                bf16x8 bfr = *(const bf16x8*)(&Wt2[ncol * 512 + ks * 32 + lk]);
#pragma unroll
                for (int m = 0; m < 4; m++)
                    acc[m][n] = __builtin_amdgcn_mfma_f32_16x16x32_bf16(a[m], bfr, acc[m][n], 0, 0, 0);
            }
        }
#pragma unroll
        for (int n = 0; n < 2; n++) {
            int col = wid * 32 + n * 16 + lr;
            float bias = b2[col];
#pragma unroll
            for (int m = 0; m < 4; m++)
#pragma unroll
                for (int r = 0; r < 4; r++) {
                    int row = m * 16 + lq + r;
                    float v = acc[m][n][r] + bias;
                    cm[SWZ(row * DDIM + col, row)] = f2bf(v);
                }
        }
    }
    __syncthreads();

    // ---- GEMM3: h1 = relu([xs|cm][64x256] @ W3[256x512] + b3) ----
    {
        f32x4 acc[4][8];
#pragma unroll
        for (int m = 0; m < 4; m++)
#pragma unroll
            for (int n = 0; n < 8; n++) acc[m][n] = (f32x4)0.0f;
#pragma unroll
        for (int ks = 0; ks < 8; ks++) {
            const unsigned short* srcT = (ks < 4) ? xs : cm;
            int kk = (ks & 3) * 32 + lk;
            bf16x8 a[4];
#pragma unroll
            for (int m = 0; m < 4; m++) {
                int row = m * 16 + lr;
                a[m] = *(const bf16x8*)(&srcT[SWZ(row * DDIM + kk, row)]);
            }
#pragma unroll
            for (int n = 0; n < 8; n++) {
                int ncol = wid * 128 + n * 16 + lr;
                bf16x8 bfr = *(const bf16x8*)(&Wt3[ncol * 256 + ks * 32 + lk]);
#pragma unroll
                for (int m = 0; m < 4; m++)
                    acc[m][n] = __builtin_amdgcn_mfma_f32_16x16x32_bf16(a[m], bfr, acc[m][n], 0, 0, 0);
            }
        }
#pragma unroll
        for (int n = 0; n < 8; n++) {
            int col = wid * 128 + n * 16 + lr;
            float bias = b3[col];
#pragma unroll
            for (int m = 0; m < 4; m++)
#pragma unroll
                for (int r = 0; r < 4; r++) {
                    int row = m * 16 + lq + r;
                    float v = fmaxf(acc[m][n][r] + bias, 0.0f);
                    h1[SWZ(row * HDIM + col, row)] = f2bf(v);
                }
        }
    }
    __syncthreads();

    // ---- GEMM4 + residual: out = x + (h1[64x512] @ W4[512x128] + b4) ----
    {
        f32x4 acc[4][2];
#pragma unroll
        for (int m = 0; m < 4; m++) { acc[m][0] = (f32x4)0.0f; acc[m][1] = (f32x4)0.0f; }
#pragma unroll
        for (int ks = 0; ks < 16; ks++) {
            bf16x8 a[4];
#pragma unroll
            for (int m = 0; m < 4; m++) {
                int row = m * 16 + lr;
                a[m] = *(const bf16x8*)(&h1[SWZ(row * HDIM + ks * 32 + lk, row)]);
            }
#pragma unroll
            for (int n = 0; n < 2; n++) {
                int ncol = wid * 32 + n * 16 + lr;
                bf16x8 bfr = *(const bf16x8*)(&Wt4[ncol * 512 + ks * 32 + lk]);
#pragma unroll
                for (int m = 0; m < 4; m++)
                    acc[m][n] = __builtin_amdgcn_mfma_f32_16x16x32_bf16(a[m], bfr, acc[m][n], 0, 0, 0);
            }
        }
#pragma unroll
        for (int n = 0; n < 2; n++) {
            int col = wid * 32 + n * 16 + lr;
            float bias = b4[col];
#pragma unroll
            for (int m = 0; m < 4; m++)
#pragma unroll
                for (int r = 0; r < 4; r++) {
                    int row = m * 16 + lq + r;
                    float v = acc[m][n][r] + bias + xg[row * DDIM + col];
                    out[(l * SDIM + row) * DDIM + col] = v;   // fp32 output
                }
        }
    }
}

extern "C" void kernel_launch(void* const* d_in, const int* in_sizes, int n_in,
                              void* d_out, int out_size, void* d_ws, size_t ws_size,
                              hipStream_t stream) {
    const float* x  = (const float*)d_in[0];
    const float* W1 = (const float*)d_in[1];
    const float* b1 = (const float*)d_in[2];
    const float* W2 = (const float*)d_in[3];
    const float* b2 = (const float*)d_in[4];
    const float* W3 = (const float*)d_in[5];
    const float* b3 = (const float*)d_in[6];
    const float* W4 = (const float*)d_in[7];
    const float* b4 = (const float*)d_in[8];
    unsigned short* ws = (unsigned short*)d_ws;
    float* out = (float*)d_out;

    kprep<<<320, 256, 0, stream>>>(W1, W2, W3, W4, ws);
    kmain<<<256, 256, 0, stream>>>(x, b1, b2, b3, b4, ws, out);
}